// Round 24
// baseline (65.547 us; speedup 1.0000x reference)
//
#include <hip/hip_runtime.h>
#include <math.h>

#define SEQ 1024
#define DM 512

typedef __attribute__((ext_vector_type(8))) short bf16x8;
typedef __attribute__((ext_vector_type(4))) short bf16x4;
typedef __attribute__((ext_vector_type(4))) float f32x4;
typedef __attribute__((ext_vector_type(4))) int i32x4;

static __device__ __forceinline__ short f2b(float f) {
    union { float f; unsigned u; } x; x.f = f;
    unsigned r = (x.u + 0x7FFFu + ((x.u >> 16) & 1u)) >> 16;
    return (short)r;
}
static __device__ __forceinline__ float b2f(short s) {
    union { unsigned u; float f; } x; x.u = ((unsigned)(unsigned short)s) << 16;
    return x.f;
}
// swizzled elem index into a [R][64] bf16 LDS tile (128B rows, XOR bank swizzle)
static __device__ __forceinline__ int sidx(int row, int col) {
    int byte = (row << 7) + (col << 1);
    byte ^= (row & 7) << 4;
    return byte >> 1;
}

static __device__ __forceinline__ void stage_f32(short* dst, const float* src, int srcStride, int tid) {
    int r = tid >> 2, c = (tid & 3) * 16;
    const float* p = src + (size_t)r * srcStride + c;
    bf16x8 v0, v1;
    #pragma unroll
    for (int e = 0; e < 8; ++e) v0[e] = f2b(p[e]);
    #pragma unroll
    for (int e = 0; e < 8; ++e) v1[e] = f2b(p[8 + e]);
    *(bf16x8*)&dst[sidx(r, c)] = v0;
    *(bf16x8*)&dst[sidx(r, c + 8)] = v1;
}
static __device__ __forceinline__ void stage_bf16(short* dst, const short* src, int srcStride, int tid) {
    int r = tid >> 2, c = (tid & 3) * 16;
    const short* p = src + (size_t)r * srcStride + c;
    bf16x8 v0 = *(const bf16x8*)p;
    bf16x8 v1 = *(const bf16x8*)(p + 8);
    *(bf16x8*)&dst[sidx(r, c)] = v0;
    *(bf16x8*)&dst[sidx(r, c + 8)] = v1;
}

// 64x64x64 MFMA block
static __device__ __forceinline__ void mma64(const short* sA, const short* sB, f32x4* acc,
                                             int w, int lr, int lg) {
    #pragma unroll
    for (int ks = 0; ks < 2; ++ks) {
        bf16x8 af = *(const bf16x8*)&sA[sidx(w * 16 + lr, ks * 32 + lg * 8)];
        #pragma unroll
        for (int nt = 0; nt < 4; ++nt) {
            bf16x8 bf = *(const bf16x8*)&sB[sidx(nt * 16 + lr, ks * 32 + lg * 8)];
            acc[nt] = __builtin_amdgcn_mfma_f32_16x16x32_bf16(af, bf, acc[nt], 0, 0, 0);
        }
    }
}

// ---------------- prep: wtrans (256) + layernorm->bf16 (2048) + nibble idx pack (1024) ----------------
__global__ __launch_bounds__(256) void prep_kernel(
    const float* __restrict__ w0, const float* __restrict__ w1,
    const float* __restrict__ w2, const float* __restrict__ w3, short* __restrict__ wt,
    const float* __restrict__ q, short* __restrict__ qnb,
    const float* __restrict__ gamma, const float* __restrict__ beta,
    const int* __restrict__ dist, const int* __restrict__ mask, unsigned char* __restrict__ idxp) {
    int blk = blockIdx.x;
    int tid = threadIdx.x;
    if (blk < 256) {
        int wsel = blk >> 6;
        int t = blk & 63;
        int tr = t >> 3, tc = t & 7;
        const float* src = wsel == 0 ? w0 : wsel == 1 ? w1 : wsel == 2 ? w2 : w3;
        short* dst = wt + (size_t)wsel * 512 * 512;
        __shared__ float tile[64][65];
        int r = tid >> 2, c = (tid & 3) * 16;
        const float* p = src + (size_t)(tr * 64 + r) * 512 + tc * 64 + c;
        #pragma unroll
        for (int e = 0; e < 16; ++e) tile[r][c + e] = p[e];
        __syncthreads();
        bf16x8 v0, v1;
        #pragma unroll
        for (int e = 0; e < 16; ++e) {
            short bv = f2b(tile[c + e][r]);
            if (e < 8) v0[e] = bv; else v1[e - 8] = bv;
        }
        short* qd = dst + (size_t)(tc * 64 + r) * 512 + tr * 64 + c;
        *(bf16x8*)qd = v0;
        *(bf16x8*)(qd + 8) = v1;
    } else if (blk < 2304) {
        int row = blk - 256;
        const float* x = q + (size_t)row * DM;
        short* y = qnb + (size_t)row * DM;
        float v1 = x[tid], v2 = x[tid + 256];
        float s = v1 + v2;
        float ss = v1 * v1 + v2 * v2;
        for (int o = 32; o > 0; o >>= 1) { s += __shfl_down(s, o); ss += __shfl_down(ss, o); }
        __shared__ float red[4], red2[4];
        __shared__ float s_mu, s_rstd;
        int wid = tid >> 6, lane = tid & 63;
        if (lane == 0) { red[wid] = s; red2[wid] = ss; }
        __syncthreads();
        if (tid == 0) {
            float ts = red[0] + red[1] + red[2] + red[3];
            float tss = red2[0] + red2[1] + red2[2] + red2[3];
            float mu = ts / DM;
            float var = tss / DM - mu * mu;
            s_mu = mu;
            s_rstd = rsqrtf(var + 1e-6f);
        }
        __syncthreads();
        float mu = s_mu, rstd = s_rstd;
        y[tid]       = f2b((v1 - mu) * rstd * gamma[tid]       + beta[tid]);
        y[tid + 256] = f2b((v2 - mu) * rstd * gamma[tid + 256] + beta[tid + 256]);
    } else {
        // nibble pack: out byte = nib(j even) | nib(j odd)<<4, nib = min(d,5) | (m==0?8:0)
        size_t base = ((size_t)(blk - 2304) * 256 + tid) * 8;
        i32x4 d0 = *(const i32x4*)(dist + base);
        i32x4 d1 = *(const i32x4*)(dist + base + 4);
        i32x4 m0 = *(const i32x4*)(mask + base);
        i32x4 m1 = *(const i32x4*)(mask + base + 4);
        int dv[8], mv[8];
        #pragma unroll
        for (int e = 0; e < 4; ++e) { dv[e] = d0[e]; dv[4 + e] = d1[e]; mv[e] = m0[e]; mv[4 + e] = m1[e]; }
        unsigned char ob[4];
        #pragma unroll
        for (int e = 0; e < 4; ++e) {
            int dA = dv[2 * e];     if (dA > 5) dA = 5;
            int dB = dv[2 * e + 1]; if (dB > 5) dB = 5;
            unsigned nA = (unsigned)dA | (mv[2 * e] == 0 ? 8u : 0u);
            unsigned nB = (unsigned)dB | (mv[2 * e + 1] == 0 ? 8u : 0u);
            ob[e] = (unsigned char)(nA | (nB << 4));
        }
        *(uchar4*)(idxp + base / 2) = *(uchar4*)ob;
    }
}

// ---------------- fused q/k/v projection GEMMs (768 blocks) ----------------
__global__ __launch_bounds__(256) void qkv_kernel(
    const short* __restrict__ qnb, const float* __restrict__ k, const float* __restrict__ v,
    const short* __restrict__ wT, short* __restrict__ qsb, short* __restrict__ khx,
    short* __restrict__ vfx) {
    __shared__ short sA[64 * 64];
    __shared__ short sB[64 * 64];
    int tid = threadIdx.x;
    int sel = blockIdx.x >> 8;
    int t = blockIdx.x & 255;
    int bx = t & 7, by = t >> 3;
    int m0 = by << 6, n0 = bx << 6;
    int w = tid >> 6, l = tid & 63;
    int lr = l & 15, lg = l >> 4;
    const short* Bt = wT + (size_t)sel * 262144;
    float scale = sel == 0 ? 0.125f : 1.0f;
    f32x4 acc[4] = {};
    for (int kt = 0; kt < 512; kt += 64) {
        __syncthreads();
        if (sel == 0) stage_bf16(sA, qnb + (size_t)m0 * 512 + kt, 512, tid);
        else          stage_f32 (sA, (sel == 1 ? k : v) + (size_t)m0 * 512 + kt, 512, tid);
        stage_bf16(sB, Bt + (size_t)n0 * 512 + kt, 512, tid);
        __syncthreads();
        mma64(sA, sB, acc, w, lr, lg);
    }
    // wave-private scratch: 1024 shorts (2KB), disjoint per wave
    short* scratch = sA + w * 1024;
    if (sel == 0) {
        #pragma unroll
        for (int nt = 0; nt < 4; ++nt)
            #pragma unroll
            for (int r = 0; r < 4; ++r)
                scratch[(lg * 4 + r) * 64 + nt * 16 + lr] = f2b(acc[nt][r] * scale);
        #pragma unroll
        for (int cc = 0; cc < 2; ++cc) {
            int c = cc * 64 + l;
            *(bf16x8*)&qsb[(size_t)(m0 + w * 16 + (c >> 3)) * 512 + n0 + (c & 7) * 8]
                = *(const bf16x8*)&scratch[c * 8];
        }
    } else if (sel == 1) {
        // K fragment block: one complete 2KB block per wave, layout == linear
        #pragma unroll
        for (int nt = 0; nt < 4; ++nt) {
            int dl = nt * 16 + lr;
            int f = dl >> 5, lgp = (dl >> 3) & 3, e = dl & 7;
            int base = ((f * 4 + lgp) * 16) * 8 + e;
            #pragma unroll
            for (int r = 0; r < 4; ++r)
                scratch[base + (lg * 4 + r) * 8] = f2b(acc[nt][r]);
        }
        int bq = m0 >> 10, jt = (m0 >> 6) & 15;
        short* blockp = khx + ((((size_t)(bq * 8 + bx) * 16 + jt) * 4 + w) << 10);
        *(bf16x8*)(blockp + l * 8)       = *(const bf16x8*)(scratch + l * 8);
        *(bf16x8*)(blockp + 512 + l * 8) = *(const bf16x8*)(scratch + 512 + l * 8);
    } else {
        // V: wave fills half a 4KB block (its rel-slice), 4x512B runs
        int bq = m0 >> 10, j6 = (m0 >> 6) & 15, p = j6 >> 1, rel = j6 & 1;
        #pragma unroll
        for (int nt = 0; nt < 4; ++nt)
            #pragma unroll
            for (int r = 0; r < 4; ++r) {
                int s = ((nt * 2 + (lg >> 1)) * 16 + lr) * 8 + (lg & 1) * 4 + r;
                scratch[s] = f2b(acc[nt][r]);
            }
        short* blockp = vfx + ((((size_t)(bq * 8 + bx) * 8 + p) * 4 + w) << 11);
        #pragma unroll
        for (int cc = 0; cc < 2; ++cc) {
            int c = cc * 64 + l;
            int s = c * 8;
            int g = s + ((c >> 5) << 8) + (rel << 8);
            *(bf16x8*)(blockp + g) = *(const bf16x8*)(scratch + s);
        }
    }
}

// ---------------- single-pass fused attention: 512 threads, 8 waves, half-length chains ----------------
// Waves 0-3 sweep jt 0-7 (strips 0-3); waves 4-7 sweep jt 8-15. Zero LDS in
// sweep; XCD swizzle; l/O reduced across 8 waves (disjoint j-ranges sum).
#define IDXSTR 520   // bytes per nibble row (512 + 8 pad)
__global__ __launch_bounds__(512) void attn_fused_kernel(
    const short* __restrict__ qsb, const short* __restrict__ khx,
    const short* __restrict__ vfx, const unsigned char* __restrict__ idxp,
    const float* __restrict__ rpr, float* __restrict__ attnp, short* __restrict__ oh) {
    int bid = ((blockIdx.x & 7) << 7) + (blockIdx.x >> 3);   // bijective, 1024 % 8 == 0
    int bh = bid >> 6, it = bid & 63;
    int b = bh >> 3, h = bh & 7;
    int i0 = it << 4;
    int tid = threadIdx.x;
    int w = tid >> 6, l = tid & 63;
    int lr = l & 15, lg = l >> 4;
    int wj = w & 3;              // j-strip within 64-col tile
    int jtb = (w >> 2) * 8;      // this wave's jt range base

    // union buffer: phase1 = sQ(2KB)+sQB(512B)+sIdx(8320B) = 10880B
    //               phase2 = sO8 f32[8][16][32] = 16KB (overlays from offset 0)
    __shared__ __align__(16) char sBuf[16384];
    __shared__ float sL[8][16];
    short* sQ = (short*)sBuf;
    float* sQB = (float*)(sBuf + 2048);
    unsigned char* sIdx = (unsigned char*)(sBuf + 2560);
    float* sO8 = (float*)sBuf;

    if (tid < 128) {
        int r = tid >> 3, c = (tid & 7) * 8;
        bf16x8 qv = *(const bf16x8*)(qsb + ((size_t)(b * SEQ + i0 + r)) * DM + h * 64 + c);
        *(bf16x8*)&sQ[sidx(r, c)] = qv;
    }
    {
        const unsigned char* ibase = idxp + ((size_t)(b * SEQ + i0)) * 512;
        int idx = tid;                      // 512 threads cover 512 of 520 chunks
        if (idx < 520) {
            int row = idx >> 5;
            int cb = (idx & 31) * 16;
            if (row < 16) {
                i32x4 v = *(const i32x4*)(ibase + (size_t)row * 512 + cb);
                *(i32x4*)&sIdx[row * IDXSTR + cb] = v;
            }
        }
    }
    __syncthreads();
    if (tid < 128) {
        int r = tid >> 3, m = tid & 7;
        if (m < 6) {
            float a = 0.f;
            #pragma unroll 8
            for (int d = 0; d < 64; ++d) a += b2f(sQ[sidx(r, d)]) * rpr[m * 64 + d];
            sQB[r * 8 + m] = a;
        }
    }
    __syncthreads();

    bf16x8 qf0 = *(const bf16x8*)&sQ[sidx(lr, lg * 8)];
    bf16x8 qf1 = *(const bf16x8*)&sQ[sidx(lr, 32 + lg * 8)];

    float qb0 = sQB[lr * 8 + 0], qb1 = sQB[lr * 8 + 1], qb2 = sQB[lr * 8 + 2];
    float qb3 = sQB[lr * 8 + 3], qb4 = sQB[lr * 8 + 4], qb5 = sQB[lr * 8 + 5];
    __syncthreads();   // everyone has Q frags + bias regs; sQ/sQB regions now dead

    float l_lane = 0.f;
    unsigned p_lo[8], p_hi[8];
    f32x4 accO[4] = {};
    const short* kblk = khx + (((size_t)bh * 16) * 4 + wj) * 1024;
    const short* vblk = vfx + (((size_t)bh * 8) * 4 + wj) * 2048;
    int fragoff = (lg * 16 + lr) * 8;
    const unsigned char* irow = sIdx + lr * IDXSTR + wj * 8 + lg * 2;

    #pragma unroll
    for (int jj = 0; jj < 8; ++jj) {
        int jt = jtb + jj;
        const short* kb = kblk + jt * 4096;
        bf16x8 kf0 = *(const bf16x8*)(kb + fragoff);
        bf16x8 kf1 = *(const bf16x8*)(kb + 512 + fragoff);
        f32x4 sf = {};
        sf = __builtin_amdgcn_mfma_f32_16x16x32_bf16(kf0, qf0, sf, 0, 0, 0);
        sf = __builtin_amdgcn_mfma_f32_16x16x32_bf16(kf1, qf1, sf, 0, 0, 0);
        unsigned u = *(const unsigned short*)(irow + jt * 32);
        float pv[4];
        #pragma unroll
        for (int r = 0; r < 4; ++r) {
            unsigned bb = (u >> (4 * r)) & 0xFu;
            unsigned dd = bb & 7u;
            float t0 = (dd & 1) ? qb1 : qb0;
            float t1 = (dd & 1) ? qb3 : qb2;
            float t2 = (dd & 1) ? qb5 : qb4;
            float u0 = (dd & 2) ? t1 : t0;
            float bias = (dd & 4) ? t2 : u0;
            float s = fminf(sf[r] + bias, 30.f);
            float p = (bb & 8) ? 0.f : __expf(s);
            pv[r] = p;
            l_lane += p;
        }
        unsigned plo, phi;
        asm("v_cvt_pk_bf16_f32 %0, %1, %2" : "=v"(plo) : "v"(pv[0]), "v"(pv[1]));
        asm("v_cvt_pk_bf16_f32 %0, %1, %2" : "=v"(phi) : "v"(pv[2]), "v"(pv[3]));
        p_lo[jj] = plo; p_hi[jj] = phi;
        if (jj & 1) {
            unsigned plo0 = p_lo[jj - 1], phi0 = p_hi[jj - 1];
            int srcA = lr + ((lg & 1) << 5);
            int srcB = srcA + 16;
            unsigned aw0 = __shfl(plo0, srcA), aw1 = __shfl(phi0, srcA);
            unsigned aw2 = __shfl(plo,  srcA), aw3 = __shfl(phi,  srcA);
            unsigned bw0 = __shfl(plo0, srcB), bw1 = __shfl(phi0, srcB);
            unsigned bw2 = __shfl(plo,  srcB), bw3 = __shfl(phi,  srcB);
            bool hi = lg >= 2;
            union { unsigned q[4]; bf16x8 v; } afu;
            afu.q[0] = hi ? aw2 : aw0;
            afu.q[1] = hi ? aw3 : aw1;
            afu.q[2] = hi ? bw2 : bw0;
            afu.q[3] = hi ? bw3 : bw1;
            bf16x8 af = afu.v;
            const short* vb = vblk + (jt >> 1) * 8192;
            #pragma unroll
            for (int nt = 0; nt < 4; ++nt) {
                bf16x8 bf = *(const bf16x8*)(vb + nt * 512 + fragoff);
                accO[nt] = __builtin_amdgcn_mfma_f32_16x16x32_bf16(af, bf, accO[nt], 0, 0, 0);
            }
        }
    }

    l_lane += __shfl_xor(l_lane, 16);
    l_lane += __shfl_xor(l_lane, 32);
    if (lg == 0) sL[w][lr] = l_lane;
    __syncthreads();   // sIdx reads complete; sL complete; sBuf becomes sO8

    // ---- O reduce pass A: cols 0-31 (accO[0..1]), 8 waves ----
    #pragma unroll
    for (int nt = 0; nt < 2; ++nt)
        #pragma unroll
        for (int r = 0; r < 4; ++r)
            sO8[w * 512 + (lg * 4 + r) * 32 + nt * 16 + lr] = accO[nt][r];
    __syncthreads();
    if (tid < 128) {
        int row = tid >> 3, c4 = (tid & 7) * 4;
        f32x4 o = *(f32x4*)&sO8[row * 32 + c4];
        float lt = sL[0][row];
        #pragma unroll
        for (int wv = 1; wv < 8; ++wv) {
            o += *(f32x4*)&sO8[wv * 512 + row * 32 + c4];
            lt += sL[wv][row];
        }
        float rl = 1.f / lt;
        bf16x4 ob;
        #pragma unroll
        for (int e = 0; e < 4; ++e) ob[e] = f2b(o[e] * rl);
        *(bf16x4*)&oh[((size_t)(b * SEQ + i0 + row)) * DM + h * 64 + c4] = ob;
    }
    __syncthreads();
    // ---- O reduce pass B: cols 32-63 (accO[2..3]) ----
    #pragma unroll
    for (int nt = 2; nt < 4; ++nt)
        #pragma unroll
        for (int r = 0; r < 4; ++r)
            sO8[w * 512 + (lg * 4 + r) * 32 + (nt - 2) * 16 + lr] = accO[nt][r];
    __syncthreads();
    if (tid < 128) {
        int row = tid >> 3, c4 = (tid & 7) * 4;
        f32x4 o = *(f32x4*)&sO8[row * 32 + c4];
        float lt = sL[0][row];
        #pragma unroll
        for (int wv = 1; wv < 8; ++wv) {
            o += *(f32x4*)&sO8[wv * 512 + row * 32 + c4];
            lt += sL[wv][row];
        }
        float rl = 1.f / lt;
        bf16x4 ob;
        #pragma unroll
        for (int e = 0; e < 4; ++e) ob[e] = f2b(o[e] * rl);
        *(bf16x4*)&oh[((size_t)(b * SEQ + i0 + row)) * DM + h * 64 + 32 + c4] = ob;
    }

    // attn write: lane owns row i=i0+lr, 4 consecutive j, its 8 jts
    float lt = sL[0][lr];
    #pragma unroll
    for (int wv = 1; wv < 8; ++wv) lt += sL[wv][lr];
    float rl = 1.f / lt;
    float* ap = attnp + ((size_t)(bh * SEQ + i0 + lr)) * SEQ + wj * 16 + lg * 4;
    #pragma unroll
    for (int jj = 0; jj < 8; ++jj) {
        unsigned plo = p_lo[jj], phi = p_hi[jj];
        f32x4 o;
        o[0] = b2f((short)(plo & 0xffff)) * rl;
        o[1] = b2f((short)(plo >> 16))    * rl;
        o[2] = b2f((short)(phi & 0xffff)) * rl;
        o[3] = b2f((short)(phi >> 16))    * rl;
        *(f32x4*)&ap[(jtb + jj) * 64] = o;
    }
}

// ---------------- fc GEMM: out = oh @ w_fc^T + q ----------------
__global__ __launch_bounds__(256) void fc_kernel(
    const short* __restrict__ oh, const short* __restrict__ BtFc,
    const float* __restrict__ Rsd, float* __restrict__ Cp) {
    __shared__ short sA[64 * 64];
    __shared__ short sB[64 * 64];
    int tid = threadIdx.x;
    int bx = blockIdx.x & 7, by = blockIdx.x >> 3;
    int m0 = by << 6, n0 = bx << 6;
    int w = tid >> 6, l = tid & 63;
    int lr = l & 15, lg = l >> 4;
    f32x4 acc[4] = {};
    for (int kt = 0; kt < 512; kt += 64) {
        __syncthreads();
        stage_bf16(sA, oh + (size_t)m0 * 512 + kt, 512, tid);
        stage_bf16(sB, BtFc + (size_t)n0 * 512 + kt, 512, tid);
        __syncthreads();
        mma64(sA, sB, acc, w, lr, lg);
    }
    #pragma unroll
    for (int nt = 0; nt < 4; ++nt)
        #pragma unroll
        for (int r = 0; r < 4; ++r) {
            int gm = m0 + w * 16 + lg * 4 + r;
            int gn = n0 + nt * 16 + lr;
            Cp[(size_t)gm * 512 + gn] = acc[nt][r] + Rsd[(size_t)gm * 512 + gn];
        }
}

extern "C" void kernel_launch(void* const* d_in, const int* in_sizes, int n_in,
                              void* d_out, int out_size, void* d_ws, size_t ws_size,
                              hipStream_t stream) {
    const float* q     = (const float*)d_in[0];
    const float* k     = (const float*)d_in[1];
    const float* v     = (const float*)d_in[2];
    const int*   mask  = (const int*)d_in[3];
    const int*   dist  = (const int*)d_in[4];
    const float* w_qs  = (const float*)d_in[5];
    const float* w_ks  = (const float*)d_in[6];
    const float* w_vs  = (const float*)d_in[7];
    const float* w_fc  = (const float*)d_in[8];
    const float* gamma = (const float*)d_in[9];
    const float* beta  = (const float*)d_in[10];
    const float* rpr   = (const float*)d_in[11];

    char* wsb = (char*)d_ws;
    short* qnb  = (short*)wsb;                                   // 2MB bf16 LN(q) (dead after qkv)
    short* oh   = (short*)wsb + 1048576;                         // 2MB
    short* wT   = (short*)(wsb + 4u * 1024 * 1024);              // 2MB
    short* qsb  = (short*)(wsb + 6u * 1024 * 1024);              // 2MB
    short* khx  = (short*)(wsb + 8u * 1024 * 1024);              // 2MB fragment-order K
    short* vfx  = (short*)(wsb + 10u * 1024 * 1024);             // 2MB fragment-order V
    unsigned char* idxp = (unsigned char*)(wsb + 12u * 1024 * 1024); // 1MB nibble-packed

    float* outp  = (float*)d_out;
    float* attnp = outp + 1048576;

    prep_kernel<<<3328, 256, 0, stream>>>(w_qs, w_ks, w_vs, w_fc, wT, q, qnb, gamma, beta, dist, mask, idxp);
    qkv_kernel<<<768, 256, 0, stream>>>(qnb, k, v, wT, qsb, khx, vfx);
    attn_fused_kernel<<<1024, 512, 0, stream>>>(qsb, khx, vfx, idxp, rpr, attnp, oh);
    fc_kernel<<<256, 256, 0, stream>>>(oh, wT + 786432, q, outp);
}

// Round 25
// 64.412 us; speedup vs baseline: 1.0176x; 1.0176x over previous
//
#include <hip/hip_runtime.h>
#include <math.h>

#define SEQ 1024
#define DM 512

typedef __attribute__((ext_vector_type(8))) short bf16x8;
typedef __attribute__((ext_vector_type(4))) short bf16x4;
typedef __attribute__((ext_vector_type(4))) float f32x4;
typedef __attribute__((ext_vector_type(4))) int i32x4;

static __device__ __forceinline__ short f2b(float f) {
    union { float f; unsigned u; } x; x.f = f;
    unsigned r = (x.u + 0x7FFFu + ((x.u >> 16) & 1u)) >> 16;
    return (short)r;
}
static __device__ __forceinline__ float b2f(short s) {
    union { unsigned u; float f; } x; x.u = ((unsigned)(unsigned short)s) << 16;
    return x.f;
}
// swizzled elem index into a [R][64] bf16 LDS tile (128B rows, XOR bank swizzle)
static __device__ __forceinline__ int sidx(int row, int col) {
    int byte = (row << 7) + (col << 1);
    byte ^= (row & 7) << 4;
    return byte >> 1;
}

static __device__ __forceinline__ void stage_f32(short* dst, const float* src, int srcStride, int tid) {
    int r = tid >> 2, c = (tid & 3) * 16;
    const float* p = src + (size_t)r * srcStride + c;
    bf16x8 v0, v1;
    #pragma unroll
    for (int e = 0; e < 8; ++e) v0[e] = f2b(p[e]);
    #pragma unroll
    for (int e = 0; e < 8; ++e) v1[e] = f2b(p[8 + e]);
    *(bf16x8*)&dst[sidx(r, c)] = v0;
    *(bf16x8*)&dst[sidx(r, c + 8)] = v1;
}
static __device__ __forceinline__ void stage_bf16(short* dst, const short* src, int srcStride, int tid) {
    int r = tid >> 2, c = (tid & 3) * 16;
    const short* p = src + (size_t)r * srcStride + c;
    bf16x8 v0 = *(const bf16x8*)p;
    bf16x8 v1 = *(const bf16x8*)(p + 8);
    *(bf16x8*)&dst[sidx(r, c)] = v0;
    *(bf16x8*)&dst[sidx(r, c + 8)] = v1;
}

// 64x64x64 MFMA block
static __device__ __forceinline__ void mma64(const short* sA, const short* sB, f32x4* acc,
                                             int w, int lr, int lg) {
    #pragma unroll
    for (int ks = 0; ks < 2; ++ks) {
        bf16x8 af = *(const bf16x8*)&sA[sidx(w * 16 + lr, ks * 32 + lg * 8)];
        #pragma unroll
        for (int nt = 0; nt < 4; ++nt) {
            bf16x8 bf = *(const bf16x8*)&sB[sidx(nt * 16 + lr, ks * 32 + lg * 8)];
            acc[nt] = __builtin_amdgcn_mfma_f32_16x16x32_bf16(af, bf, acc[nt], 0, 0, 0);
        }
    }
}

// ---------------- prep: wtrans (256) + layernorm->bf16 (2048) + nibble idx pack (1024) ----------------
__global__ __launch_bounds__(256) void prep_kernel(
    const float* __restrict__ w0, const float* __restrict__ w1,
    const float* __restrict__ w2, const float* __restrict__ w3, short* __restrict__ wt,
    const float* __restrict__ q, short* __restrict__ qnb,
    const float* __restrict__ gamma, const float* __restrict__ beta,
    const int* __restrict__ dist, const int* __restrict__ mask, unsigned char* __restrict__ idxp) {
    int blk = blockIdx.x;
    int tid = threadIdx.x;
    if (blk < 256) {
        int wsel = blk >> 6;
        int t = blk & 63;
        int tr = t >> 3, tc = t & 7;
        const float* src = wsel == 0 ? w0 : wsel == 1 ? w1 : wsel == 2 ? w2 : w3;
        short* dst = wt + (size_t)wsel * 512 * 512;
        __shared__ float tile[64][65];
        int r = tid >> 2, c = (tid & 3) * 16;
        const float* p = src + (size_t)(tr * 64 + r) * 512 + tc * 64 + c;
        #pragma unroll
        for (int e = 0; e < 16; ++e) tile[r][c + e] = p[e];
        __syncthreads();
        bf16x8 v0, v1;
        #pragma unroll
        for (int e = 0; e < 16; ++e) {
            short bv = f2b(tile[c + e][r]);
            if (e < 8) v0[e] = bv; else v1[e - 8] = bv;
        }
        short* qd = dst + (size_t)(tc * 64 + r) * 512 + tr * 64 + c;
        *(bf16x8*)qd = v0;
        *(bf16x8*)(qd + 8) = v1;
    } else if (blk < 2304) {
        int row = blk - 256;
        const float* x = q + (size_t)row * DM;
        short* y = qnb + (size_t)row * DM;
        float v1 = x[tid], v2 = x[tid + 256];
        float s = v1 + v2;
        float ss = v1 * v1 + v2 * v2;
        for (int o = 32; o > 0; o >>= 1) { s += __shfl_down(s, o); ss += __shfl_down(ss, o); }
        __shared__ float red[4], red2[4];
        __shared__ float s_mu, s_rstd;
        int wid = tid >> 6, lane = tid & 63;
        if (lane == 0) { red[wid] = s; red2[wid] = ss; }
        __syncthreads();
        if (tid == 0) {
            float ts = red[0] + red[1] + red[2] + red[3];
            float tss = red2[0] + red2[1] + red2[2] + red2[3];
            float mu = ts / DM;
            float var = tss / DM - mu * mu;
            s_mu = mu;
            s_rstd = rsqrtf(var + 1e-6f);
        }
        __syncthreads();
        float mu = s_mu, rstd = s_rstd;
        y[tid]       = f2b((v1 - mu) * rstd * gamma[tid]       + beta[tid]);
        y[tid + 256] = f2b((v2 - mu) * rstd * gamma[tid + 256] + beta[tid + 256]);
    } else {
        // nibble pack: out byte = nib(j even) | nib(j odd)<<4, nib = min(d,5) | (m==0?8:0)
        size_t base = ((size_t)(blk - 2304) * 256 + tid) * 8;
        i32x4 d0 = *(const i32x4*)(dist + base);
        i32x4 d1 = *(const i32x4*)(dist + base + 4);
        i32x4 m0 = *(const i32x4*)(mask + base);
        i32x4 m1 = *(const i32x4*)(mask + base + 4);
        int dv[8], mv[8];
        #pragma unroll
        for (int e = 0; e < 4; ++e) { dv[e] = d0[e]; dv[4 + e] = d1[e]; mv[e] = m0[e]; mv[4 + e] = m1[e]; }
        unsigned char ob[4];
        #pragma unroll
        for (int e = 0; e < 4; ++e) {
            int dA = dv[2 * e];     if (dA > 5) dA = 5;
            int dB = dv[2 * e + 1]; if (dB > 5) dB = 5;
            unsigned nA = (unsigned)dA | (mv[2 * e] == 0 ? 8u : 0u);
            unsigned nB = (unsigned)dB | (mv[2 * e + 1] == 0 ? 8u : 0u);
            ob[e] = (unsigned char)(nA | (nB << 4));
        }
        *(uchar4*)(idxp + base / 2) = *(uchar4*)ob;
    }
}

// ---------------- fused q/k/v projection GEMMs (768 blocks) ----------------
__global__ __launch_bounds__(256) void qkv_kernel(
    const short* __restrict__ qnb, const float* __restrict__ k, const float* __restrict__ v,
    const short* __restrict__ wT, short* __restrict__ qsb, short* __restrict__ khx,
    short* __restrict__ vfx) {
    __shared__ short sA[64 * 64];
    __shared__ short sB[64 * 64];
    int tid = threadIdx.x;
    int sel = blockIdx.x >> 8;
    int t = blockIdx.x & 255;
    int bx = t & 7, by = t >> 3;
    int m0 = by << 6, n0 = bx << 6;
    int w = tid >> 6, l = tid & 63;
    int lr = l & 15, lg = l >> 4;
    const short* Bt = wT + (size_t)sel * 262144;
    float scale = sel == 0 ? 0.125f : 1.0f;
    f32x4 acc[4] = {};
    for (int kt = 0; kt < 512; kt += 64) {
        __syncthreads();
        if (sel == 0) stage_bf16(sA, qnb + (size_t)m0 * 512 + kt, 512, tid);
        else          stage_f32 (sA, (sel == 1 ? k : v) + (size_t)m0 * 512 + kt, 512, tid);
        stage_bf16(sB, Bt + (size_t)n0 * 512 + kt, 512, tid);
        __syncthreads();
        mma64(sA, sB, acc, w, lr, lg);
    }
    // wave-private scratch: 1024 shorts (2KB), disjoint per wave
    short* scratch = sA + w * 1024;
    if (sel == 0) {
        #pragma unroll
        for (int nt = 0; nt < 4; ++nt)
            #pragma unroll
            for (int r = 0; r < 4; ++r)
                scratch[(lg * 4 + r) * 64 + nt * 16 + lr] = f2b(acc[nt][r] * scale);
        #pragma unroll
        for (int cc = 0; cc < 2; ++cc) {
            int c = cc * 64 + l;
            *(bf16x8*)&qsb[(size_t)(m0 + w * 16 + (c >> 3)) * 512 + n0 + (c & 7) * 8]
                = *(const bf16x8*)&scratch[c * 8];
        }
    } else if (sel == 1) {
        // K fragment block: one complete 2KB block per wave, layout == linear
        #pragma unroll
        for (int nt = 0; nt < 4; ++nt) {
            int dl = nt * 16 + lr;
            int f = dl >> 5, lgp = (dl >> 3) & 3, e = dl & 7;
            int base = ((f * 4 + lgp) * 16) * 8 + e;
            #pragma unroll
            for (int r = 0; r < 4; ++r)
                scratch[base + (lg * 4 + r) * 8] = f2b(acc[nt][r]);
        }
        int bq = m0 >> 10, jt = (m0 >> 6) & 15;
        short* blockp = khx + ((((size_t)(bq * 8 + bx) * 16 + jt) * 4 + w) << 10);
        *(bf16x8*)(blockp + l * 8)       = *(const bf16x8*)(scratch + l * 8);
        *(bf16x8*)(blockp + 512 + l * 8) = *(const bf16x8*)(scratch + 512 + l * 8);
    } else {
        // V: wave fills half a 4KB block (its rel-slice), 4x512B runs
        int bq = m0 >> 10, j6 = (m0 >> 6) & 15, p = j6 >> 1, rel = j6 & 1;
        #pragma unroll
        for (int nt = 0; nt < 4; ++nt)
            #pragma unroll
            for (int r = 0; r < 4; ++r) {
                int s = ((nt * 2 + (lg >> 1)) * 16 + lr) * 8 + (lg & 1) * 4 + r;
                scratch[s] = f2b(acc[nt][r]);
            }
        short* blockp = vfx + ((((size_t)(bq * 8 + bx) * 8 + p) * 4 + w) << 11);
        #pragma unroll
        for (int cc = 0; cc < 2; ++cc) {
            int c = cc * 64 + l;
            int s = c * 8;
            int g = s + ((c >> 5) << 8) + (rel << 8);
            *(bf16x8*)(blockp + g) = *(const bf16x8*)(scratch + s);
        }
    }
}

// ---------------- single-pass fused attention: ZERO LDS in the j-sweep ----------------
// XCD swizzle + setprio(1) around MFMA clusters (T5: waves free-run, no
// sweep barriers -> scheduler can favor MFMA-entering waves).
#define IDXSTR 520   // bytes per nibble row (512 + 8 pad)
__global__ __launch_bounds__(256) void attn_fused_kernel(
    const short* __restrict__ qsb, const short* __restrict__ khx,
    const short* __restrict__ vfx, const unsigned char* __restrict__ idxp,
    const float* __restrict__ rpr, float* __restrict__ attnp, short* __restrict__ oh) {
    int bid = ((blockIdx.x & 7) << 7) + (blockIdx.x >> 3);   // bijective, 1024 % 8 == 0
    int bh = bid >> 6, it = bid & 63;
    int b = bh >> 3, h = bh & 7;
    int i0 = it << 4;
    int tid = threadIdx.x;
    int w = tid >> 6, l = tid & 63;
    int lr = l & 15, lg = l >> 4;

    // union buffer: phase1 = sQ(2KB)+sQB(512B)+sIdx(8320B) = 10880B
    //               phase2 = sO8 f32[4][16][32] = 8KB (overlays from offset 0)
    __shared__ __align__(16) char sBuf[10880];
    __shared__ float sL[4][16];
    short* sQ = (short*)sBuf;
    float* sQB = (float*)(sBuf + 2048);
    unsigned char* sIdx = (unsigned char*)(sBuf + 2560);
    float* sO8 = (float*)sBuf;

    if (tid < 128) {
        int r = tid >> 3, c = (tid & 7) * 8;
        bf16x8 qv = *(const bf16x8*)(qsb + ((size_t)(b * SEQ + i0 + r)) * DM + h * 64 + c);
        *(bf16x8*)&sQ[sidx(r, c)] = qv;
    }
    {
        const unsigned char* ibase = idxp + ((size_t)(b * SEQ + i0)) * 512;
        #pragma unroll
        for (int p = 0; p < 2; ++p) {
            int idx = p * 256 + tid;
            int row = idx >> 5;
            int cb = (idx & 31) * 16;
            i32x4 v = *(const i32x4*)(ibase + (size_t)row * 512 + cb);
            *(i32x4*)&sIdx[row * IDXSTR + cb] = v;
        }
    }
    __syncthreads();
    if (tid < 128) {
        int r = tid >> 3, m = tid & 7;
        if (m < 6) {
            float a = 0.f;
            #pragma unroll 8
            for (int d = 0; d < 64; ++d) a += b2f(sQ[sidx(r, d)]) * rpr[m * 64 + d];
            sQB[r * 8 + m] = a;
        }
    }
    __syncthreads();

    bf16x8 qf0 = *(const bf16x8*)&sQ[sidx(lr, lg * 8)];
    bf16x8 qf1 = *(const bf16x8*)&sQ[sidx(lr, 32 + lg * 8)];

    float qb0 = sQB[lr * 8 + 0], qb1 = sQB[lr * 8 + 1], qb2 = sQB[lr * 8 + 2];
    float qb3 = sQB[lr * 8 + 3], qb4 = sQB[lr * 8 + 4], qb5 = sQB[lr * 8 + 5];
    __syncthreads();   // everyone has Q frags + bias regs; sQ/sQB regions now dead

    float l_lane = 0.f;
    unsigned p_lo[16], p_hi[16];
    f32x4 accO[4] = {};
    const short* kblk = khx + (((size_t)bh * 16) * 4 + w) * 1024;
    const short* vblk = vfx + (((size_t)bh * 8) * 4 + w) * 2048;
    int fragoff = (lg * 16 + lr) * 8;
    const unsigned char* irow = sIdx + lr * IDXSTR + w * 8 + lg * 2;

    #pragma unroll
    for (int jt = 0; jt < 16; ++jt) {
        const short* kb = kblk + jt * 4096;
        bf16x8 kf0 = *(const bf16x8*)(kb + fragoff);
        bf16x8 kf1 = *(const bf16x8*)(kb + 512 + fragoff);
        f32x4 sf = {};
        __builtin_amdgcn_s_setprio(1);
        sf = __builtin_amdgcn_mfma_f32_16x16x32_bf16(kf0, qf0, sf, 0, 0, 0);
        sf = __builtin_amdgcn_mfma_f32_16x16x32_bf16(kf1, qf1, sf, 0, 0, 0);
        __builtin_amdgcn_s_setprio(0);
        unsigned u = *(const unsigned short*)(irow + jt * 32);
        float pv[4];
        #pragma unroll
        for (int r = 0; r < 4; ++r) {
            unsigned bb = (u >> (4 * r)) & 0xFu;
            unsigned dd = bb & 7u;
            float t0 = (dd & 1) ? qb1 : qb0;
            float t1 = (dd & 1) ? qb3 : qb2;
            float t2 = (dd & 1) ? qb5 : qb4;
            float u0 = (dd & 2) ? t1 : t0;
            float bias = (dd & 4) ? t2 : u0;
            float s = fminf(sf[r] + bias, 30.f);
            float p = (bb & 8) ? 0.f : __expf(s);
            pv[r] = p;
            l_lane += p;
        }
        unsigned plo, phi;
        asm("v_cvt_pk_bf16_f32 %0, %1, %2" : "=v"(plo) : "v"(pv[0]), "v"(pv[1]));
        asm("v_cvt_pk_bf16_f32 %0, %1, %2" : "=v"(phi) : "v"(pv[2]), "v"(pv[3]));
        p_lo[jt] = plo; p_hi[jt] = phi;
        if (jt & 1) {
            unsigned plo0 = p_lo[jt - 1], phi0 = p_hi[jt - 1];
            int srcA = lr + ((lg & 1) << 5);
            int srcB = srcA + 16;
            unsigned aw0 = __shfl(plo0, srcA), aw1 = __shfl(phi0, srcA);
            unsigned aw2 = __shfl(plo,  srcA), aw3 = __shfl(phi,  srcA);
            unsigned bw0 = __shfl(plo0, srcB), bw1 = __shfl(phi0, srcB);
            unsigned bw2 = __shfl(plo,  srcB), bw3 = __shfl(phi,  srcB);
            bool hi = lg >= 2;
            union { unsigned q[4]; bf16x8 v; } afu;
            afu.q[0] = hi ? aw2 : aw0;
            afu.q[1] = hi ? aw3 : aw1;
            afu.q[2] = hi ? bw2 : bw0;
            afu.q[3] = hi ? bw3 : bw1;
            bf16x8 af = afu.v;
            const short* vb = vblk + (jt >> 1) * 8192;
            __builtin_amdgcn_s_setprio(1);
            #pragma unroll
            for (int nt = 0; nt < 4; ++nt) {
                bf16x8 bf = *(const bf16x8*)(vb + nt * 512 + fragoff);
                accO[nt] = __builtin_amdgcn_mfma_f32_16x16x32_bf16(af, bf, accO[nt], 0, 0, 0);
            }
            __builtin_amdgcn_s_setprio(0);
        }
    }

    l_lane += __shfl_xor(l_lane, 16);
    l_lane += __shfl_xor(l_lane, 32);
    if (lg == 0) sL[w][lr] = l_lane;
    __syncthreads();   // sIdx reads complete; sL complete; sBuf becomes sO8

    // ---- O reduce pass A: cols 0-31 (accO[0..1]) ----
    #pragma unroll
    for (int nt = 0; nt < 2; ++nt)
        #pragma unroll
        for (int r = 0; r < 4; ++r)
            sO8[w * 512 + (lg * 4 + r) * 32 + nt * 16 + lr] = accO[nt][r];
    __syncthreads();
    if (tid < 128) {
        int row = tid >> 3, c4 = (tid & 7) * 4;
        f32x4 o = *(f32x4*)&sO8[row * 32 + c4];
        o += *(f32x4*)&sO8[512 + row * 32 + c4];
        o += *(f32x4*)&sO8[1024 + row * 32 + c4];
        o += *(f32x4*)&sO8[1536 + row * 32 + c4];
        float rl = 1.f / (sL[0][row] + sL[1][row] + sL[2][row] + sL[3][row]);
        bf16x4 ob;
        #pragma unroll
        for (int e = 0; e < 4; ++e) ob[e] = f2b(o[e] * rl);
        *(bf16x4*)&oh[((size_t)(b * SEQ + i0 + row)) * DM + h * 64 + c4] = ob;
    }
    __syncthreads();
    // ---- O reduce pass B: cols 32-63 (accO[2..3]) ----
    #pragma unroll
    for (int nt = 2; nt < 4; ++nt)
        #pragma unroll
        for (int r = 0; r < 4; ++r)
            sO8[w * 512 + (lg * 4 + r) * 32 + (nt - 2) * 16 + lr] = accO[nt][r];
    __syncthreads();
    if (tid < 128) {
        int row = tid >> 3, c4 = (tid & 7) * 4;
        f32x4 o = *(f32x4*)&sO8[row * 32 + c4];
        o += *(f32x4*)&sO8[512 + row * 32 + c4];
        o += *(f32x4*)&sO8[1024 + row * 32 + c4];
        o += *(f32x4*)&sO8[1536 + row * 32 + c4];
        float rl = 1.f / (sL[0][row] + sL[1][row] + sL[2][row] + sL[3][row]);
        bf16x4 ob;
        #pragma unroll
        for (int e = 0; e < 4; ++e) ob[e] = f2b(o[e] * rl);
        *(bf16x4*)&oh[((size_t)(b * SEQ + i0 + row)) * DM + h * 64 + 32 + c4] = ob;
    }

    // attn write from registers: lane owns row i=i0+lr, 4 consecutive j per jt
    float rl = 1.f / (sL[0][lr] + sL[1][lr] + sL[2][lr] + sL[3][lr]);
    float* ap = attnp + ((size_t)(bh * SEQ + i0 + lr)) * SEQ + w * 16 + lg * 4;
    #pragma unroll
    for (int jt = 0; jt < 16; ++jt) {
        unsigned plo = p_lo[jt], phi = p_hi[jt];
        f32x4 o;
        o[0] = b2f((short)(plo & 0xffff)) * rl;
        o[1] = b2f((short)(plo >> 16))    * rl;
        o[2] = b2f((short)(phi & 0xffff)) * rl;
        o[3] = b2f((short)(phi >> 16))    * rl;
        *(f32x4*)&ap[jt * 64] = o;
    }
}

// ---------------- fc GEMM: out = oh @ w_fc^T + q ----------------
__global__ __launch_bounds__(256) void fc_kernel(
    const short* __restrict__ oh, const short* __restrict__ BtFc,
    const float* __restrict__ Rsd, float* __restrict__ Cp) {
    __shared__ short sA[64 * 64];
    __shared__ short sB[64 * 64];
    int tid = threadIdx.x;
    int bx = blockIdx.x & 7, by = blockIdx.x >> 3;
    int m0 = by << 6, n0 = bx << 6;
    int w = tid >> 6, l = tid & 63;
    int lr = l & 15, lg = l >> 4;
    f32x4 acc[4] = {};
    for (int kt = 0; kt < 512; kt += 64) {
        __syncthreads();
        stage_bf16(sA, oh + (size_t)m0 * 512 + kt, 512, tid);
        stage_bf16(sB, BtFc + (size_t)n0 * 512 + kt, 512, tid);
        __syncthreads();
        mma64(sA, sB, acc, w, lr, lg);
    }
    #pragma unroll
    for (int nt = 0; nt < 4; ++nt)
        #pragma unroll
        for (int r = 0; r < 4; ++r) {
            int gm = m0 + w * 16 + lg * 4 + r;
            int gn = n0 + nt * 16 + lr;
            Cp[(size_t)gm * 512 + gn] = acc[nt][r] + Rsd[(size_t)gm * 512 + gn];
        }
}

extern "C" void kernel_launch(void* const* d_in, const int* in_sizes, int n_in,
                              void* d_out, int out_size, void* d_ws, size_t ws_size,
                              hipStream_t stream) {
    const float* q     = (const float*)d_in[0];
    const float* k     = (const float*)d_in[1];
    const float* v     = (const float*)d_in[2];
    const int*   mask  = (const int*)d_in[3];
    const int*   dist  = (const int*)d_in[4];
    const float* w_qs  = (const float*)d_in[5];
    const float* w_ks  = (const float*)d_in[6];
    const float* w_vs  = (const float*)d_in[7];
    const float* w_fc  = (const float*)d_in[8];
    const float* gamma = (const float*)d_in[9];
    const float* beta  = (const float*)d_in[10];
    const float* rpr   = (const float*)d_in[11];

    char* wsb = (char*)d_ws;
    short* qnb  = (short*)wsb;                                   // 2MB bf16 LN(q) (dead after qkv)
    short* oh   = (short*)wsb + 1048576;                         // 2MB
    short* wT   = (short*)(wsb + 4u * 1024 * 1024);              // 2MB
    short* qsb  = (short*)(wsb + 6u * 1024 * 1024);              // 2MB
    short* khx  = (short*)(wsb + 8u * 1024 * 1024);              // 2MB fragment-order K
    short* vfx  = (short*)(wsb + 10u * 1024 * 1024);             // 2MB fragment-order V
    unsigned char* idxp = (unsigned char*)(wsb + 12u * 1024 * 1024); // 1MB nibble-packed

    float* outp  = (float*)d_out;
    float* attnp = outp + 1048576;

    prep_kernel<<<3328, 256, 0, stream>>>(w_qs, w_ks, w_vs, w_fc, wT, q, qnb, gamma, beta, dist, mask, idxp);
    qkv_kernel<<<768, 256, 0, stream>>>(qnb, k, v, wT, qsb, khx, vfx);
    attn_fused_kernel<<<1024, 256, 0, stream>>>(qsb, khx, vfx, idxp, rpr, attnp, oh);
    fc_kernel<<<256, 256, 0, stream>>>(oh, wT + 786432, q, outp);
}